// Round 1
// baseline (463.689 us; speedup 1.0000x reference)
//
#include <hip/hip_runtime.h>
#include <hip/hip_bf16.h>
#include <cstddef>

typedef unsigned int  u32;
typedef unsigned short u16;
typedef __attribute__((ext_vector_type(8))) short short8;
typedef __attribute__((ext_vector_type(4))) float f32x4;
typedef __attribute__((ext_vector_type(2))) float f32x2;
typedef __attribute__((ext_vector_type(4))) int i32x4;

#define DV 128
#define DH 128
#define DE 16
#define DO 128

// ---------- bf16 helpers (bit tricks, RNE) ----------
__device__ inline float bf_lo(u32 u){ return __uint_as_float(u << 16); }
__device__ inline float bf_hi(u32 u){ return __uint_as_float(u & 0xFFFF0000u); }
__device__ inline u32 fpack2(float a, float b){
  u32 ua = __float_as_uint(a), ub = __float_as_uint(b);
  ua += 0x7FFFu + ((ua >> 16) & 1u);
  ub += 0x7FFFu + ((ub >> 16) & 1u);
  return (ua >> 16) | (ub & 0xFFFF0000u);
}
__device__ inline u16 f2bf(float a){
  u32 ua = __float_as_uint(a); ua += 0x7FFFu + ((ua >> 16) & 1u); return (u16)(ua >> 16);
}

// ---------- fp8 (OCP e4m3) helpers: 4 channels per u32 ----------
__device__ inline void acc_fp8(u32 s, float& a0, float& a1, float& a2, float& a3){
  f32x2 lo = __builtin_amdgcn_cvt_pk_f32_fp8((int)s, false);
  f32x2 hi = __builtin_amdgcn_cvt_pk_f32_fp8((int)s, true);
  a0 += lo.x; a1 += lo.y; a2 += hi.x; a3 += hi.y;
}
__device__ inline u32 pack_fp8(float a0, float a1, float a2, float a3){
  int o = __builtin_amdgcn_cvt_pk_fp8_f32(a0, a1, 0, false);
  o = __builtin_amdgcn_cvt_pk_fp8_f32(a2, a3, o, true);
  return (u32)o;
}

// nontemporal int4 load: streamed index lists must not evict gather tables from L2
__device__ inline i32x4 ld_nt4(const int* p){
  return __builtin_nontemporal_load((const i32x4*)p);
}

// ---------- CSR build ----------
__global__ void k_init(int* cnt, float* poolp, int n, int pn){
  int v = blockIdx.x * blockDim.x + threadIdx.x;
  if (v < n) cnt[v] = 0;
  if (v < pn) poolp[v] = 0.f;
}
// count + per-edge rank within dst bucket; ALSO stream-convert edge_attr -> bf16 table.
// Each thread handles 8 fp32 channels (half an edge row); 2 threads/edge, e2 threads total.
__global__ void k_count(const int* dst, const float* edge_attr, int* cnt, int* rank,
                        u32* ea_pack, int e2){
  int j = blockIdx.x * blockDim.x + threadIdx.x;
  if (j < e2){
    rank[j] = atomicAdd(&cnt[dst[j]], 1);
    float4 f0 = *(const float4*)(edge_attr + (size_t)j * 8);
    float4 f1 = *(const float4*)(edge_attr + (size_t)j * 8 + 4);
    uint4 o;
    o.x = fpack2(f0.x, f0.y); o.y = fpack2(f0.z, f0.w);
    o.z = fpack2(f1.x, f1.y); o.w = fpack2(f1.z, f1.w);
    *(uint4*)(ea_pack + (size_t)j * 4) = o;
  }
}
// scan of PADDED counts: pc = (cnt+7)&~7  (rows padded to multiple of 8)
__global__ __launch_bounds__(256) void k_scan1(const int* cnt, int* partial, int* bsums, int n){
  __shared__ int lds[256];
  int t = threadIdx.x;
  int base = blockIdx.x * 1024 + t * 4;
  int v0=0,v1=0,v2=0,v3=0;
  if (base + 3 < n){ int4 q = *(const int4*)(cnt + base); v0=q.x; v1=q.y; v2=q.z; v3=q.w; }
  else {
    if (base + 0 < n) v0 = cnt[base];
    if (base + 1 < n) v1 = cnt[base+1];
    if (base + 2 < n) v2 = cnt[base+2];
  }
  v0 = (v0 + 7) & ~7; v1 = (v1 + 7) & ~7; v2 = (v2 + 7) & ~7; v3 = (v3 + 7) & ~7;
  v1 += v0; v2 += v1; v3 += v2;
  lds[t] = v3; __syncthreads();
  for (int off = 1; off < 256; off <<= 1){
    int x = (t >= off) ? lds[t - off] : 0;
    __syncthreads();
    lds[t] += x;
    __syncthreads();
  }
  int add = (t > 0) ? lds[t - 1] : 0;
  if (base + 3 < n){
    int4 q; q.x = v0+add; q.y = v1+add; q.z = v2+add; q.w = v3+add;
    *(int4*)(partial + base) = q;
  } else {
    if (base + 0 < n) partial[base]   = v0 + add;
    if (base + 1 < n) partial[base+1] = v1 + add;
    if (base + 2 < n) partial[base+2] = v2 + add;
  }
  if (t == 255) bsums[blockIdx.x] = lds[255];
}
__global__ void k_scan2(const int* bsums, int* bexc, int nb){
  __shared__ int lds[128];
  int t = threadIdx.x;
  lds[t] = (t < nb) ? bsums[t] : 0;
  __syncthreads();
  for (int off = 1; off < 128; off <<= 1){
    int x = (t >= off) ? lds[t - off] : 0;
    __syncthreads();
    lds[t] += x;
    __syncthreads();
  }
  if (t < nb) bexc[t] = (t > 0) ? lds[t - 1] : 0;
}
// fused: row_ptr finalize + dinv/degf prep + graph-start detection (was 3 kernels)
__global__ void k_scan3f(const int* partial, const int* bexc, int* row_ptr,
                         const int* cnt, float* dinv, float* degf,
                         const int* batch, int* startg, int n, int g){
  int i = blockIdx.x * blockDim.x + threadIdx.x;
  if (i < n){
    row_ptr[i + 1] = partial[i] + bexc[i >> 10];
    if (i == 0) row_ptr[0] = 0;
    float c = (float)(cnt[i] + 1);   // in-degree + self-loop
    dinv[i] = rsqrtf(c);
    degf[i] = c;
    int b = batch[i];
    int prev = (i == 0) ? -1 : batch[i - 1];
    for (int q = prev + 1; q <= b; ++q) startg[q] = i;
    if (i == n - 1){ for (int q = b + 1; q <= g; ++q) startg[q] = n; }
  }
}
// fused scatter + pad (+ zero-row init). Pad slots are disjoint from scattered slots
// (rank < cnt[d] always), so both can run in one grid. Split planes:
//   ce_src[pos] = src<<5  (direct u32-index into 32-word fp8 rows; pad marker = n<<5)
//   ce_eid[pos] = j>>1    (undirected edge id, pre-shifted; pad eid = 0)
__global__ void k_scatterpad(const int* src, const int* dst, const int* rank,
                             const int* row_ptr, const int* cnt,
                             int* ce_src, int* ce_eid,
                             u32* xws_zrow, u32* h_zrow, int e2, int n){
  int j = blockIdx.x * blockDim.x + threadIdx.x;
  if (j < e2){
    int d = dst[j];
    int pos = row_ptr[d] + rank[j];
    ce_src[pos] = src[j] << 5;
    ce_eid[pos] = j >> 1;
  }
  if (j < n){
    int s = row_ptr[j] + cnt[j], e = row_ptr[j + 1];
    int nm = n << 5;
    for (int i = s; i < e; ++i){ ce_src[i] = nm; ce_eid[i] = 0; }
  }
  if (j < 32){
    xws_zrow[j] = 0u;
    h_zrow[j] = 0u;
  }
}

// ---------- fold W_le@W_bot and biases into the h2 GEMM weight ----------
__global__ __launch_bounds__(128) void k_wcombo(const float* W_lin, const float* b_lin,
                                                const float* W_le, const float* b_le, float* Wfull){
  int r = blockIdx.x, c = threadIdx.x;
  if (r < DH){
    Wfull[r * DH + c] = W_lin[r * DH + c];            // W_top copy
  } else if (r < DH + DE){
    int i = r - DH;                                   // combo row i = W_le[i,:] @ W_bot
    float acc = 0.f;
    #pragma unroll 8
    for (int k = 0; k < DH; k += 4){
      float4 wl = *(const float4*)(W_le + i * DH + k);   // broadcast
      acc += wl.x * W_lin[(size_t)(DH + k    ) * DH + c];
      acc += wl.y * W_lin[(size_t)(DH + k + 1) * DH + c];
      acc += wl.z * W_lin[(size_t)(DH + k + 2) * DH + c];
      acc += wl.w * W_lin[(size_t)(DH + k + 3) * DH + c];
    }
    Wfull[r * DH + c] = acc;
  } else if (r == 144){
    float acc = b_lin[c];                             // bias row: b_le @ W_bot + b_lin
    #pragma unroll 8
    for (int k = 0; k < DH; k += 4){
      float4 bl = *(const float4*)(b_le + k);
      acc += bl.x * W_lin[(size_t)(DH + k    ) * DH + c];
      acc += bl.y * W_lin[(size_t)(DH + k + 1) * DH + c];
      acc += bl.z * W_lin[(size_t)(DH + k + 2) * DH + c];
      acc += bl.w * W_lin[(size_t)(DH + k + 3) * DH + c];
    }
    Wfull[r * DH + c] = acc;
  } else {
    Wfull[r * DH + c] = 0.f;
  }
}

// ---------- MFMA GEMM: [M,K] @ [K,128] -> bf16 / fp8 / fused graph-pool ----------
// POOL: h2 is only consumed by mean-pooling, so reduce the 64-row tile here and
// atomicAdd one 128-float partial per block (f32, one LESS rounding than old bf16 path).
template<int K, bool RELU, bool ABF16, bool SCALE, bool OFP8, bool POOL>
__global__ __launch_bounds__(256) void k_gemm_mfma(const void* Ap, const float* W, u32* outb,
                                                   const float* scale, int M,
                                                   const int* batchp, float* poolp){
  constexpr int SA = K + 8;      // u16 stride
  constexpr int CS = 136;        // Ct stride (u16)
  __shared__ u16 Wt[128 * SA];   // W transposed, bf16: Wt[c][k]
  __shared__ u16 At[64 * SA];    // A tile bf16 (reused as Ct / pool scratch in epilogue)
  int tid = threadIdx.x;
  int row0 = blockIdx.x * 64;

  // ---- stage Wt: coalesced fp32 reads, transposed bf16x8 LDS writes ----
  {
    int c = tid & 127, half = tid >> 7;
    for (int g = half; g < K / 8; g += 2){
      int k0 = g * 8;
      float w0 = W[(size_t)(k0+0)*128 + c], w1 = W[(size_t)(k0+1)*128 + c];
      float w2 = W[(size_t)(k0+2)*128 + c], w3 = W[(size_t)(k0+3)*128 + c];
      float w4 = W[(size_t)(k0+4)*128 + c], w5 = W[(size_t)(k0+5)*128 + c];
      float w6 = W[(size_t)(k0+6)*128 + c], w7 = W[(size_t)(k0+7)*128 + c];
      uint4 pk;
      pk.x = fpack2(w0, w1); pk.y = fpack2(w2, w3);
      pk.z = fpack2(w4, w5); pk.w = fpack2(w6, w7);
      *(uint4*)&Wt[c * SA + k0] = pk;
    }
  }
  // ---- stage At ----
  constexpr int CH = K / 8;
  for (int idx = tid; idx < 64 * CH; idx += 256){
    int r = idx / CH, ch = idx - r * CH;
    int gr = row0 + r; if (gr > M - 1) gr = M - 1;
    uint4 pk;
    if (ABF16){
      pk = *(const uint4*)((const u16*)Ap + (size_t)gr * K + ch * 8);
    } else {
      const float* A = (const float*)Ap + (size_t)gr * K + ch * 8;
      float4 q0 = *(const float4*)A;
      float4 q1 = *(const float4*)(A + 4);
      pk.x = fpack2(q0.x, q0.y); pk.y = fpack2(q0.z, q0.w);
      pk.z = fpack2(q1.x, q1.y); pk.w = fpack2(q1.z, q1.w);
    }
    *(uint4*)&At[r * SA + ch * 8] = pk;
  }
  __syncthreads();

  // ---- MFMA main loop ----
  int l = tid & 63, w = tid >> 6;
  int m = l & 15, quad = l >> 4;
  f32x4 acc[8];
  #pragma unroll
  for (int ct = 0; ct < 8; ++ct) acc[ct] = (f32x4){0.f, 0.f, 0.f, 0.f};
  #pragma unroll
  for (int ks = 0; ks < K; ks += 32){
    short8 av = *(const short8*)&At[(w * 16 + m) * SA + ks + quad * 8];
    #pragma unroll
    for (int ct = 0; ct < 8; ++ct){
      short8 bv = *(const short8*)&Wt[(ct * 16 + m) * SA + ks + quad * 8];
      acc[ct] = __builtin_amdgcn_mfma_f32_16x16x32_bf16(av, bv, acc[ct], 0, 0, 0);
    }
  }
  __syncthreads();   // done reading At — reuse as Ct / pool scratch

  if (POOL){
    // C layout: row = w*16 + quad*4 + r, col = ct*16 + m
    float* ps = (float*)At;
    int rbase = w * 16 + quad * 4;
    int g0 = batchp[row0];
    int glast = batchp[(row0 + 63 < M) ? (row0 + 63) : (M - 1)];
    if (g0 == glast){
      // fast path: all valid rows of this tile belong to graph g0
      #pragma unroll
      for (int ct = 0; ct < 8; ++ct){
        float s = 0.f;
        #pragma unroll
        for (int r = 0; r < 4; ++r){
          float vv = fmaxf(acc[ct][r], 0.f);
          if (row0 + rbase + r < M) s += vv;     // exclude tail-clamped rows
        }
        s += __shfl_xor(s, 16);                  // reduce over quad (4 rows -> 16)
        s += __shfl_xor(s, 32);
        if (quad == 0) ps[w * 128 + ct * 16 + m] = s;
      }
      __syncthreads();
      if (tid < 128){
        float t = ps[tid] + ps[128 + tid] + ps[256 + tid] + ps[384 + tid];
        atomicAdd(&poolp[g0 * DO + tid], t);
      }
    } else {
      // boundary path (<=63 blocks total): per-row atomics
      #pragma unroll
      for (int ct = 0; ct < 8; ++ct){
        #pragma unroll
        for (int r = 0; r < 4; ++r){
          int row = row0 + rbase + r;
          if (row < M){
            float vv = fmaxf(acc[ct][r], 0.f);
            atomicAdd(&poolp[batchp[row] * DO + ct * 16 + m], vv);
          }
        }
      }
    }
    return;
  }

  // ---- epilogue: scale/relu, bf16 pack into Ct ----
  u16* Ct = At;
  float sc[4];
  if (SCALE){
    #pragma unroll
    for (int r = 0; r < 4; ++r){
      int gr = row0 + w * 16 + quad * 4 + r;
      sc[r] = scale[gr < M ? gr : (M - 1)];
    }
  }
  #pragma unroll
  for (int ct = 0; ct < 8; ++ct){
    #pragma unroll
    for (int r = 0; r < 4; ++r){
      float vv = acc[ct][r];
      if (SCALE) vv *= sc[r];
      if (RELU)  vv = fmaxf(vv, 0.f);
      Ct[(w * 16 + quad * 4 + r) * CS + ct * 16 + m] = f2bf(vv);
    }
  }
  __syncthreads();
  if (OFP8){
    // convert bf16 Ct -> fp8 rows (128 B), coalesced uint2 stores
    for (int idx = tid; idx < 64 * 16; idx += 256){
      int r = idx >> 4, c8 = idx & 15;
      int gr = row0 + r;
      if (gr < M){
        uint4 qv = *(const uint4*)&Ct[r * CS + c8 * 8];
        uint2 ov;
        ov.x = (u32)__builtin_amdgcn_cvt_pk_fp8_f32(bf_lo(qv.y), bf_hi(qv.y),
               __builtin_amdgcn_cvt_pk_fp8_f32(bf_lo(qv.x), bf_hi(qv.x), 0, false), true);
        ov.y = (u32)__builtin_amdgcn_cvt_pk_fp8_f32(bf_lo(qv.w), bf_hi(qv.w),
               __builtin_amdgcn_cvt_pk_fp8_f32(bf_lo(qv.z), bf_hi(qv.z), 0, false), true);
        *(uint2*)(outb + (size_t)gr * 32 + c8 * 2) = ov;
      }
    }
  } else {
    for (int idx = tid; idx < 64 * 16; idx += 256){
      int r = idx >> 4, ch = idx & 15;
      int gr = row0 + r;
      if (gr < M){
        uint4 q = *(const uint4*)&Ct[r * CS + ch * 8];
        *(uint4*)(outb + (size_t)gr * 64 + ch * 4) = q;
      }
    }
  }
}

// ---------- phase 1: fp8 table, 2 nodes/wave, software-pipelined 16-deep gathers ----------
// ce_src holds src<<5: gather index is (A.x + ln) directly; nt loads keep tables hot in L2
__global__ __launch_bounds__(256) void k_phase1(const u32* xws8, const int* row_ptr, const int* ce_src,
                                                const float* dinv, const float* b_gcn, u32* h8, int n){
  int lane = threadIdx.x & 63;
  int ln = lane & 31;
  int v = blockIdx.x * 8 + ((threadIdx.x >> 6) << 1) + (lane >> 5);
  if (v >= n) return;
  u32 sp = xws8[(size_t)v * 32 + ln];
  float a0 = 0.f, a1 = 0.f, a2 = 0.f, a3 = 0.f;
  acc_fp8(sp, a0, a1, a2, a3);
  int e0 = row_ptr[v], e1 = row_ptr[v + 1];
  int i = e0;
  u32 q0=0,q1=0,q2=0,q3=0,q4=0,q5=0,q6=0,q7=0;
  if (i < e1){
    i32x4 A = ld_nt4(ce_src + i);
    i32x4 B = ld_nt4(ce_src + i + 4);
    q0 = xws8[A.x + ln]; q1 = xws8[A.y + ln]; q2 = xws8[A.z + ln]; q3 = xws8[A.w + ln];
    q4 = xws8[B.x + ln]; q5 = xws8[B.y + ln]; q6 = xws8[B.z + ln]; q7 = xws8[B.w + ln];
  }
  for (; i + 8 < e1; i += 8){
    i32x4 A = ld_nt4(ce_src + i + 8);
    i32x4 B = ld_nt4(ce_src + i + 12);
    u32 p0 = xws8[A.x + ln], p1 = xws8[A.y + ln];
    u32 p2 = xws8[A.z + ln], p3 = xws8[A.w + ln];
    u32 p4 = xws8[B.x + ln], p5 = xws8[B.y + ln];
    u32 p6 = xws8[B.z + ln], p7 = xws8[B.w + ln];
    acc_fp8(q0, a0, a1, a2, a3); acc_fp8(q1, a0, a1, a2, a3);
    acc_fp8(q2, a0, a1, a2, a3); acc_fp8(q3, a0, a1, a2, a3);
    acc_fp8(q4, a0, a1, a2, a3); acc_fp8(q5, a0, a1, a2, a3);
    acc_fp8(q6, a0, a1, a2, a3); acc_fp8(q7, a0, a1, a2, a3);
    q0=p0; q1=p1; q2=p2; q3=p3; q4=p4; q5=p5; q6=p6; q7=p7;
  }
  if (i < e1){
    acc_fp8(q0, a0, a1, a2, a3); acc_fp8(q1, a0, a1, a2, a3);
    acc_fp8(q2, a0, a1, a2, a3); acc_fp8(q3, a0, a1, a2, a3);
    acc_fp8(q4, a0, a1, a2, a3); acc_fp8(q5, a0, a1, a2, a3);
    acc_fp8(q6, a0, a1, a2, a3); acc_fp8(q7, a0, a1, a2, a3);
  }
  float dv = dinv[v];
  float4 bg = *(const float4*)(b_gcn + ln * 4);
  a0 = fmaxf(fmaf(dv, a0, bg.x), 0.f);
  a1 = fmaxf(fmaf(dv, a1, bg.y), 0.f);
  a2 = fmaxf(fmaf(dv, a2, bg.z), 0.f);
  a3 = fmaxf(fmaf(dv, a3, bg.w), 0.f);
  h8[(size_t)v * 32 + ln] = pack_fp8(a0, a1, a2, a3);
}

// ---------- phase 2: fp8 h-table + bf16 ea-table, split src/eid planes ----------
__global__ __launch_bounds__(256) void k_phase2(const u32* h8, const int* row_ptr,
                                                const int* ce_src, const int* ce_eid,
                                                const u16* ea_bf, const float* degf,
                                                u16* A2b, int n){
  int lane = threadIdx.x & 63;
  int ln = lane & 31;
  int half = lane >> 5;
  int v = blockIdx.x * 8 + ((threadIdx.x >> 6) << 1) + half;
  if (v >= n) return;
  u32 sp = h8[(size_t)v * 32 + ln];
  float a0 = 0.f, a1 = 0.f, a2 = 0.f, a3 = 0.f;
  acc_fp8(sp, a0, a1, a2, a3);
  float es = 0.f;                  // channel ln&15, slot-group ln>>4 (4 edges each)
  int ch = ln & 15, grp = ln >> 4;
  int nmark = n << 5;
  int e0 = row_ptr[v], e1 = row_ptr[v + 1];
  int i = e0;
  u32 q0=0,q1=0,q2=0,q3=0,q4=0,q5=0,q6=0,q7=0;
  i32x4 As = (i32x4)0, Bs = (i32x4)0, Ae = (i32x4)0, Be = (i32x4)0;
  if (i < e1){
    As = ld_nt4(ce_src + i);     Bs = ld_nt4(ce_src + i + 4);
    Ae = ld_nt4(ce_eid + i);     Be = ld_nt4(ce_eid + i + 4);
    q0 = h8[As.x + ln]; q1 = h8[As.y + ln]; q2 = h8[As.z + ln]; q3 = h8[As.w + ln];
    q4 = h8[Bs.x + ln]; q5 = h8[Bs.y + ln]; q6 = h8[Bs.z + ln]; q7 = h8[Bs.w + ln];
  }
  for (; i + 8 < e1; i += 8){
    i32x4 As2 = ld_nt4(ce_src + i + 8);   i32x4 Bs2 = ld_nt4(ce_src + i + 12);
    i32x4 Ae2 = ld_nt4(ce_eid + i + 8);   i32x4 Be2 = ld_nt4(ce_eid + i + 12);
    // ea slots for CURRENT block from regs (grp 0 -> edges 0-3, grp 1 -> edges 4-7)
    int s0x = grp ? Bs.x : As.x, s0e = grp ? Be.x : Ae.x;
    int s1x = grp ? Bs.y : As.y, s1e = grp ? Be.y : Ae.y;
    int s2x = grp ? Bs.z : As.z, s2e = grp ? Be.z : Ae.z;
    int s3x = grp ? Bs.w : As.w, s3e = grp ? Be.w : Ae.w;
    float v0 = bf_lo((u32)ea_bf[(size_t)s0e * 16 + ch]);
    float v1 = bf_lo((u32)ea_bf[(size_t)s1e * 16 + ch]);
    float v2 = bf_lo((u32)ea_bf[(size_t)s2e * 16 + ch]);
    float v3 = bf_lo((u32)ea_bf[(size_t)s3e * 16 + ch]);
    // next block's gathers
    u32 p0 = h8[As2.x + ln], p1 = h8[As2.y + ln];
    u32 p2 = h8[As2.z + ln], p3 = h8[As2.w + ln];
    u32 p4 = h8[Bs2.x + ln], p5 = h8[Bs2.y + ln];
    u32 p6 = h8[Bs2.z + ln], p7 = h8[Bs2.w + ln];
    // consume current
    acc_fp8(q0, a0, a1, a2, a3); acc_fp8(q1, a0, a1, a2, a3);
    acc_fp8(q2, a0, a1, a2, a3); acc_fp8(q3, a0, a1, a2, a3);
    acc_fp8(q4, a0, a1, a2, a3); acc_fp8(q5, a0, a1, a2, a3);
    acc_fp8(q6, a0, a1, a2, a3); acc_fp8(q7, a0, a1, a2, a3);
    es = fmaf((s0x != nmark) ? 1.f : 0.f, v0, es);
    es = fmaf((s1x != nmark) ? 1.f : 0.f, v1, es);
    es = fmaf((s2x != nmark) ? 1.f : 0.f, v2, es);
    es = fmaf((s3x != nmark) ? 1.f : 0.f, v3, es);
    q0=p0; q1=p1; q2=p2; q3=p3; q4=p4; q5=p5; q6=p6; q7=p7;
    As=As2; Bs=Bs2; Ae=Ae2; Be=Be2;
  }
  if (i < e1){
    int s0x = grp ? Bs.x : As.x, s0e = grp ? Be.x : Ae.x;
    int s1x = grp ? Bs.y : As.y, s1e = grp ? Be.y : Ae.y;
    int s2x = grp ? Bs.z : As.z, s2e = grp ? Be.z : Ae.z;
    int s3x = grp ? Bs.w : As.w, s3e = grp ? Be.w : Ae.w;
    float v0 = bf_lo((u32)ea_bf[(size_t)s0e * 16 + ch]);
    float v1 = bf_lo((u32)ea_bf[(size_t)s1e * 16 + ch]);
    float v2 = bf_lo((u32)ea_bf[(size_t)s2e * 16 + ch]);
    float v3 = bf_lo((u32)ea_bf[(size_t)s3e * 16 + ch]);
    acc_fp8(q0, a0, a1, a2, a3); acc_fp8(q1, a0, a1, a2, a3);
    acc_fp8(q2, a0, a1, a2, a3); acc_fp8(q3, a0, a1, a2, a3);
    acc_fp8(q4, a0, a1, a2, a3); acc_fp8(q5, a0, a1, a2, a3);
    acc_fp8(q6, a0, a1, a2, a3); acc_fp8(q7, a0, a1, a2, a3);
    es = fmaf((s0x != nmark) ? 1.f : 0.f, v0, es);
    es = fmaf((s1x != nmark) ? 1.f : 0.f, v1, es);
    es = fmaf((s2x != nmark) ? 1.f : 0.f, v2, es);
    es = fmaf((s3x != nmark) ? 1.f : 0.f, v3, es);
  }
  // within-half reduction over the 2 slot groups, then wave-uniform pair pick
  es += __shfl_xor(es, 16);
  float c0v = __shfl(es, half * 32 + (ln & 7) * 2);
  float c1v = __shfl(es, half * 32 + (ln & 7) * 2 + 1);
  u32* rowp = (u32*)(A2b + (size_t)v * 160);
  uint2 o; o.x = fpack2(a0, a1); o.y = fpack2(a2, a3);
  *(uint2*)(rowp + ln * 2) = o;
  if (ln < 8){
    rowp[64 + ln] = fpack2(c0v + 1.0f, c1v + 1.0f);
  } else if (ln < 16){
    rowp[64 + ln] = (ln == 8) ? (u32)f2bf(degf[v]) : 0u;
  }
}

// ---------- final: mean + linear (pool partials come from gemm2's fused epilogue) ----------
__global__ __launch_bounds__(128) void k_poolb_final(const float* poolp, const int* start,
                                                     const float* W_out, const float* b_out,
                                                     float* out){
  __shared__ float pl[DH];
  int g = blockIdx.x, c = threadIdx.x;
  int cntg = start[g + 1] - start[g]; if (cntg < 1) cntg = 1;
  pl[c] = poolp[g * DO + c] / (float)cntg;
  __syncthreads();
  float acc = b_out[c];
  for (int k = 0; k < DH; ++k) acc += pl[k] * W_out[k * DO + c];
  out[g * DO + c] = acc;
}

extern "C" void kernel_launch(void* const* d_in, const int* in_sizes, int n_in,
                              void* d_out, int out_size, void* d_ws, size_t ws_size,
                              hipStream_t stream){
  const float* x         = (const float*)d_in[0];
  const int*   edge_index= (const int*)  d_in[1];
  const float* edge_attr = (const float*)d_in[2];
  const int*   batch     = (const int*)  d_in[3];
  const float* W_gcn     = (const float*)d_in[4];
  const float* b_gcn     = (const float*)d_in[5];
  const float* W_le      = (const float*)d_in[6];
  const float* b_le      = (const float*)d_in[7];
  const float* W_lin     = (const float*)d_in[8];
  const float* b_lin     = (const float*)d_in[9];
  const float* W_out     = (const float*)d_in[10];
  const float* b_out     = (const float*)d_in[11];
  float* out = (float*)d_out;

  const int n  = in_sizes[0] / DV;       // 100000
  const int e2 = in_sizes[1] / 2;        // 1600000 directed edges
  const int g  = out_size / DO;          // 64
  const int* srcp = edge_index;
  const int* dstp = edge_index + e2;
  const int e2pad = e2 + 7 * n + 8;      // CSR capacity with per-row pad-to-8

  char* ws = (char*)d_ws;
  size_t off = 0;
  auto alloc = [&](size_t bytes) -> char* {
    char* p = ws + off; off = (off + bytes + 255) & ~(size_t)255; return p;
  };

  int*   cnt     = (int*)  alloc((size_t)n * 4);
  int*   row_ptr = (int*)  alloc((size_t)(n + 1) * 4);
  int*   rank    = (int*)  alloc((size_t)e2 * 4);
  int*   partial = (int*)  alloc((size_t)n * 4);
  int*   bsums   = (int*)  alloc(512);
  int*   bexc    = (int*)  alloc(512);
  float* dinv    = (float*)alloc((size_t)n * 4);
  float* degf    = (float*)alloc((size_t)n * 4);
  int*   startg  = (int*)  alloc((size_t)(g + 1) * 4);
  float* poolp   = (float*)alloc((size_t)g * DO * 4);
  float* Wfull   = (float*)alloc(160 * DH * 4);
  u32*   h8      = (u32*)  alloc((size_t)(n + 1) * 128);   // fp8 rows, +1 zero row
  int*   ce_src  = (int*)  alloc((size_t)e2pad * 4);
  int*   ce_eid  = (int*)  alloc((size_t)e2pad * 4);
  u32*   ea_bf   = (u32*)  alloc((size_t)e2 * 16);         // bf16 ea table: E rows x 16ch x 2B
  // region A: xws8 (fp8, [N+1,128B]) later overwritten by A2 (bf16, [N,160])
  size_t szXW = (size_t)(n + 1) * 128, szA2 = (size_t)n * 160 * 2;
  char* regionA = alloc(szA2 > szXW ? szA2 : szXW);
  u32* xws8 = (u32*)regionA;
  u16* A2b  = (u16*)regionA;

  const int nb1024 = (n + 1023) / 1024;  // must be <= 128 for k_scan2

  k_init      <<<(n + 255) / 256, 256, 0, stream>>>(cnt, poolp, n, g * DO);
  k_count     <<<(e2 + 255) / 256, 256, 0, stream>>>(dstp, edge_attr, cnt, rank, ea_bf, e2);
  k_scan1     <<<nb1024, 256, 0, stream>>>(cnt, partial, bsums, n);
  k_scan2     <<<1, 128, 0, stream>>>(bsums, bexc, nb1024);
  k_scan3f    <<<(n + 255) / 256, 256, 0, stream>>>(partial, bexc, row_ptr, cnt, dinv, degf,
                                                    batch, startg, n, g);
  k_scatterpad<<<(e2 + 255) / 256, 256, 0, stream>>>(srcp, dstp, rank, row_ptr, cnt,
                                                     ce_src, ce_eid,
                                                     xws8 + (size_t)n * 32, h8 + (size_t)n * 32,
                                                     e2, n);
  k_wcombo    <<<160, 128, 0, stream>>>(W_lin, b_lin, W_le, b_le, Wfull);

  k_gemm_mfma<DV, false, false, true, true, false>
      <<<(n + 63) / 64, 256, 0, stream>>>(x, W_gcn, xws8, dinv, n, nullptr, nullptr);
  k_phase1    <<<(n + 7) / 8, 256, 0, stream>>>(xws8, row_ptr, ce_src, dinv, b_gcn, h8, n);
  k_phase2    <<<(n + 7) / 8, 256, 0, stream>>>(h8, row_ptr, ce_src, ce_eid,
                                                (const u16*)ea_bf, degf, A2b, n);
  k_gemm_mfma<160, true, true, false, false, true>
      <<<(n + 63) / 64, 256, 0, stream>>>(A2b, Wfull, (u32*)nullptr, (const float*)nullptr,
                                          n, batch, poolp);
  k_poolb_final<<<g, 128, 0, stream>>>(poolp, startg, W_out, b_out, out);
}

// Round 2
// 427.014 us; speedup vs baseline: 1.0859x; 1.0859x over previous
//
#include <hip/hip_runtime.h>
#include <hip/hip_bf16.h>
#include <cstddef>

typedef unsigned int  u32;
typedef unsigned short u16;
typedef __attribute__((ext_vector_type(8))) short short8;
typedef __attribute__((ext_vector_type(4))) float f32x4;
typedef __attribute__((ext_vector_type(2))) float f32x2;

#define DV 128
#define DH 128
#define DE 16
#define DO 128

// ---------- bf16 helpers (bit tricks, RNE) ----------
__device__ inline float bf_lo(u32 u){ return __uint_as_float(u << 16); }
__device__ inline float bf_hi(u32 u){ return __uint_as_float(u & 0xFFFF0000u); }
__device__ inline u32 fpack2(float a, float b){
  u32 ua = __float_as_uint(a), ub = __float_as_uint(b);
  ua += 0x7FFFu + ((ua >> 16) & 1u);
  ub += 0x7FFFu + ((ub >> 16) & 1u);
  return (ua >> 16) | (ub & 0xFFFF0000u);
}
__device__ inline u16 f2bf(float a){
  u32 ua = __float_as_uint(a); ua += 0x7FFFu + ((ua >> 16) & 1u); return (u16)(ua >> 16);
}

// ---------- fp8 (OCP e4m3) helpers: 4 channels per u32 ----------
__device__ inline void acc_fp8(u32 s, float& a0, float& a1, float& a2, float& a3){
  f32x2 lo = __builtin_amdgcn_cvt_pk_f32_fp8((int)s, false);
  f32x2 hi = __builtin_amdgcn_cvt_pk_f32_fp8((int)s, true);
  a0 += lo.x; a1 += lo.y; a2 += hi.x; a3 += hi.y;
}
__device__ inline u32 pack_fp8(float a0, float a1, float a2, float a3){
  int o = __builtin_amdgcn_cvt_pk_fp8_f32(a0, a1, 0, false);
  o = __builtin_amdgcn_cvt_pk_fp8_f32(a2, a3, o, true);
  return (u32)o;
}

// ---------- CSR build ----------
__global__ void k_init(int* cnt, float* poolp, int n, int pn){
  int v = blockIdx.x * blockDim.x + threadIdx.x;
  if (v < n) cnt[v] = 0;
  if (v < pn) poolp[v] = 0.f;
}
// count + per-edge rank within dst bucket; ALSO stream-convert edge_attr -> bf16 table.
__global__ void k_count(const int* dst, const float* edge_attr, int* cnt, int* rank,
                        u32* ea_pack, int e2){
  int j = blockIdx.x * blockDim.x + threadIdx.x;
  if (j < e2){
    rank[j] = atomicAdd(&cnt[dst[j]], 1);
    float4 f0 = *(const float4*)(edge_attr + (size_t)j * 8);
    float4 f1 = *(const float4*)(edge_attr + (size_t)j * 8 + 4);
    uint4 o;
    o.x = fpack2(f0.x, f0.y); o.y = fpack2(f0.z, f0.w);
    o.z = fpack2(f1.x, f1.y); o.w = fpack2(f1.z, f1.w);
    *(uint4*)(ea_pack + (size_t)j * 4) = o;
  }
}
// scan of PADDED counts: pc = (cnt+7)&~7  (rows padded to multiple of 8)
__global__ __launch_bounds__(256) void k_scan1(const int* cnt, int* partial, int* bsums, int n){
  __shared__ int lds[256];
  int t = threadIdx.x;
  int base = blockIdx.x * 1024 + t * 4;
  int v0=0,v1=0,v2=0,v3=0;
  if (base + 3 < n){ int4 q = *(const int4*)(cnt + base); v0=q.x; v1=q.y; v2=q.z; v3=q.w; }
  else {
    if (base + 0 < n) v0 = cnt[base];
    if (base + 1 < n) v1 = cnt[base+1];
    if (base + 2 < n) v2 = cnt[base+2];
  }
  v0 = (v0 + 7) & ~7; v1 = (v1 + 7) & ~7; v2 = (v2 + 7) & ~7; v3 = (v3 + 7) & ~7;
  v1 += v0; v2 += v1; v3 += v2;
  lds[t] = v3; __syncthreads();
  for (int off = 1; off < 256; off <<= 1){
    int x = (t >= off) ? lds[t - off] : 0;
    __syncthreads();
    lds[t] += x;
    __syncthreads();
  }
  int add = (t > 0) ? lds[t - 1] : 0;
  if (base + 3 < n){
    int4 q; q.x = v0+add; q.y = v1+add; q.z = v2+add; q.w = v3+add;
    *(int4*)(partial + base) = q;
  } else {
    if (base + 0 < n) partial[base]   = v0 + add;
    if (base + 1 < n) partial[base+1] = v1 + add;
    if (base + 2 < n) partial[base+2] = v2 + add;
  }
  if (t == 255) bsums[blockIdx.x] = lds[255];
}
__global__ void k_scan2(const int* bsums, int* bexc, int nb){
  __shared__ int lds[128];
  int t = threadIdx.x;
  lds[t] = (t < nb) ? bsums[t] : 0;
  __syncthreads();
  for (int off = 1; off < 128; off <<= 1){
    int x = (t >= off) ? lds[t - off] : 0;
    __syncthreads();
    lds[t] += x;
    __syncthreads();
  }
  if (t < nb) bexc[t] = (t > 0) ? lds[t - 1] : 0;
}
// fused: row_ptr finalize + dinv/degf prep + graph-start detection
__global__ void k_scan3f(const int* partial, const int* bexc, int* row_ptr,
                         const int* cnt, float* dinv, float* degf,
                         const int* batch, int* startg, int n, int g){
  int i = blockIdx.x * blockDim.x + threadIdx.x;
  if (i < n){
    row_ptr[i + 1] = partial[i] + bexc[i >> 10];
    if (i == 0) row_ptr[0] = 0;
    float c = (float)(cnt[i] + 1);   // in-degree + self-loop
    dinv[i] = rsqrtf(c);
    degf[i] = c;
    int b = batch[i];
    int prev = (i == 0) ? -1 : batch[i - 1];
    for (int q = prev + 1; q <= b; ++q) startg[q] = i;
    if (i == n - 1){ for (int q = b + 1; q <= g; ++q) startg[q] = n; }
  }
}
// fused scatter + pad (+ zero-row init). SINGLE interleaved int2 store per edge
// (r1's split planes doubled partial-line writebacks: WRITE_SIZE 108MB, 74us).
//   ce[pos] = { src<<5 (direct index into 32-word fp8 rows; pad marker n<<5),
//               j>>1   (undirected edge id, pre-shifted; pad eid 0) }
__global__ void k_scatterpad(const int* src, const int* dst, const int* rank,
                             const int* row_ptr, const int* cnt, int2* ce,
                             u32* xws_zrow, u32* h_zrow, int e2, int n){
  int j = blockIdx.x * blockDim.x + threadIdx.x;
  if (j < e2){
    int d = dst[j];
    int pos = row_ptr[d] + rank[j];
    ce[pos] = make_int2(src[j] << 5, j >> 1);
  }
  if (j < n){
    int s = row_ptr[j] + cnt[j], e = row_ptr[j + 1];
    int2 pd = make_int2(n << 5, 0);
    for (int i = s; i < e; ++i) ce[i] = pd;
  }
  if (j < 32){
    xws_zrow[j] = 0u;
    h_zrow[j] = 0u;
  }
}

// ---------- fold W_le@W_bot and biases into the h2 GEMM weight ----------
__global__ __launch_bounds__(128) void k_wcombo(const float* W_lin, const float* b_lin,
                                                const float* W_le, const float* b_le, float* Wfull){
  int r = blockIdx.x, c = threadIdx.x;
  if (r < DH){
    Wfull[r * DH + c] = W_lin[r * DH + c];            // W_top copy
  } else if (r < DH + DE){
    int i = r - DH;                                   // combo row i = W_le[i,:] @ W_bot
    float acc = 0.f;
    #pragma unroll 8
    for (int k = 0; k < DH; k += 4){
      float4 wl = *(const float4*)(W_le + i * DH + k);   // broadcast
      acc += wl.x * W_lin[(size_t)(DH + k    ) * DH + c];
      acc += wl.y * W_lin[(size_t)(DH + k + 1) * DH + c];
      acc += wl.z * W_lin[(size_t)(DH + k + 2) * DH + c];
      acc += wl.w * W_lin[(size_t)(DH + k + 3) * DH + c];
    }
    Wfull[r * DH + c] = acc;
  } else if (r == 144){
    float acc = b_lin[c];                             // bias row: b_le @ W_bot + b_lin
    #pragma unroll 8
    for (int k = 0; k < DH; k += 4){
      float4 bl = *(const float4*)(b_le + k);
      acc += bl.x * W_lin[(size_t)(DH + k    ) * DH + c];
      acc += bl.y * W_lin[(size_t)(DH + k + 1) * DH + c];
      acc += bl.z * W_lin[(size_t)(DH + k + 2) * DH + c];
      acc += bl.w * W_lin[(size_t)(DH + k + 3) * DH + c];
    }
    Wfull[r * DH + c] = acc;
  } else {
    Wfull[r * DH + c] = 0.f;
  }
}

// ---------- MFMA GEMM: [M,K] @ [K,128] -> bf16 / fp8 / fused graph-pool ----------
template<int K, bool RELU, bool ABF16, bool SCALE, bool OFP8, bool POOL>
__global__ __launch_bounds__(256) void k_gemm_mfma(const void* Ap, const float* W, u32* outb,
                                                   const float* scale, int M,
                                                   const int* batchp, float* poolp){
  constexpr int SA = K + 8;      // u16 stride
  constexpr int CS = 136;        // Ct stride (u16)
  __shared__ u16 Wt[128 * SA];   // W transposed, bf16: Wt[c][k]
  __shared__ u16 At[64 * SA];    // A tile bf16 (reused as Ct / pool scratch in epilogue)
  int tid = threadIdx.x;
  int row0 = blockIdx.x * 64;

  // ---- stage Wt: coalesced fp32 reads, transposed bf16x8 LDS writes ----
  {
    int c = tid & 127, half = tid >> 7;
    for (int g = half; g < K / 8; g += 2){
      int k0 = g * 8;
      float w0 = W[(size_t)(k0+0)*128 + c], w1 = W[(size_t)(k0+1)*128 + c];
      float w2 = W[(size_t)(k0+2)*128 + c], w3 = W[(size_t)(k0+3)*128 + c];
      float w4 = W[(size_t)(k0+4)*128 + c], w5 = W[(size_t)(k0+5)*128 + c];
      float w6 = W[(size_t)(k0+6)*128 + c], w7 = W[(size_t)(k0+7)*128 + c];
      uint4 pk;
      pk.x = fpack2(w0, w1); pk.y = fpack2(w2, w3);
      pk.z = fpack2(w4, w5); pk.w = fpack2(w6, w7);
      *(uint4*)&Wt[c * SA + k0] = pk;
    }
  }
  // ---- stage At ----
  constexpr int CH = K / 8;
  for (int idx = tid; idx < 64 * CH; idx += 256){
    int r = idx / CH, ch = idx - r * CH;
    int gr = row0 + r; if (gr > M - 1) gr = M - 1;
    uint4 pk;
    if (ABF16){
      pk = *(const uint4*)((const u16*)Ap + (size_t)gr * K + ch * 8);
    } else {
      const float* A = (const float*)Ap + (size_t)gr * K + ch * 8;
      float4 q0 = *(const float4*)A;
      float4 q1 = *(const float4*)(A + 4);
      pk.x = fpack2(q0.x, q0.y); pk.y = fpack2(q0.z, q0.w);
      pk.z = fpack2(q1.x, q1.y); pk.w = fpack2(q1.z, q1.w);
    }
    *(uint4*)&At[r * SA + ch * 8] = pk;
  }
  __syncthreads();

  // ---- MFMA main loop ----
  int l = tid & 63, w = tid >> 6;
  int m = l & 15, quad = l >> 4;
  f32x4 acc[8];
  #pragma unroll
  for (int ct = 0; ct < 8; ++ct) acc[ct] = (f32x4){0.f, 0.f, 0.f, 0.f};
  #pragma unroll
  for (int ks = 0; ks < K; ks += 32){
    short8 av = *(const short8*)&At[(w * 16 + m) * SA + ks + quad * 8];
    #pragma unroll
    for (int ct = 0; ct < 8; ++ct){
      short8 bv = *(const short8*)&Wt[(ct * 16 + m) * SA + ks + quad * 8];
      acc[ct] = __builtin_amdgcn_mfma_f32_16x16x32_bf16(av, bv, acc[ct], 0, 0, 0);
    }
  }
  __syncthreads();   // done reading At — reuse as Ct / pool scratch

  if (POOL){
    // C layout: row = w*16 + quad*4 + r, col = ct*16 + m
    float* ps = (float*)At;
    int rbase = w * 16 + quad * 4;
    int g0 = batchp[row0];
    int glast = batchp[(row0 + 63 < M) ? (row0 + 63) : (M - 1)];
    if (g0 == glast){
      // fast path: all valid rows of this tile belong to graph g0
      #pragma unroll
      for (int ct = 0; ct < 8; ++ct){
        float s = 0.f;
        #pragma unroll
        for (int r = 0; r < 4; ++r){
          float vv = fmaxf(acc[ct][r], 0.f);
          if (row0 + rbase + r < M) s += vv;     // exclude tail-clamped rows
        }
        s += __shfl_xor(s, 16);                  // reduce over quad (4 rows -> 16)
        s += __shfl_xor(s, 32);
        if (quad == 0) ps[w * 128 + ct * 16 + m] = s;
      }
      __syncthreads();
      if (tid < 128){
        float t = ps[tid] + ps[128 + tid] + ps[256 + tid] + ps[384 + tid];
        atomicAdd(&poolp[g0 * DO + tid], t);
      }
    } else {
      // boundary path (<=63 blocks total): per-row atomics
      #pragma unroll
      for (int ct = 0; ct < 8; ++ct){
        #pragma unroll
        for (int r = 0; r < 4; ++r){
          int row = row0 + rbase + r;
          if (row < M){
            float vv = fmaxf(acc[ct][r], 0.f);
            atomicAdd(&poolp[batchp[row] * DO + ct * 16 + m], vv);
          }
        }
      }
    }
    return;
  }

  // ---- epilogue: scale/relu, bf16 pack into Ct ----
  u16* Ct = At;
  float sc[4];
  if (SCALE){
    #pragma unroll
    for (int r = 0; r < 4; ++r){
      int gr = row0 + w * 16 + quad * 4 + r;
      sc[r] = scale[gr < M ? gr : (M - 1)];
    }
  }
  #pragma unroll
  for (int ct = 0; ct < 8; ++ct){
    #pragma unroll
    for (int r = 0; r < 4; ++r){
      float vv = acc[ct][r];
      if (SCALE) vv *= sc[r];
      if (RELU)  vv = fmaxf(vv, 0.f);
      Ct[(w * 16 + quad * 4 + r) * CS + ct * 16 + m] = f2bf(vv);
    }
  }
  __syncthreads();
  if (OFP8){
    // convert bf16 Ct -> fp8 rows (128 B), coalesced uint2 stores
    for (int idx = tid; idx < 64 * 16; idx += 256){
      int r = idx >> 4, c8 = idx & 15;
      int gr = row0 + r;
      if (gr < M){
        uint4 qv = *(const uint4*)&Ct[r * CS + c8 * 8];
        uint2 ov;
        ov.x = (u32)__builtin_amdgcn_cvt_pk_fp8_f32(bf_lo(qv.y), bf_hi(qv.y),
               __builtin_amdgcn_cvt_pk_fp8_f32(bf_lo(qv.x), bf_hi(qv.x), 0, false), true);
        ov.y = (u32)__builtin_amdgcn_cvt_pk_fp8_f32(bf_lo(qv.w), bf_hi(qv.w),
               __builtin_amdgcn_cvt_pk_fp8_f32(bf_lo(qv.z), bf_hi(qv.z), 0, false), true);
        *(uint2*)(outb + (size_t)gr * 32 + c8 * 2) = ov;
      }
    }
  } else {
    for (int idx = tid; idx < 64 * 16; idx += 256){
      int r = idx >> 4, ch = idx & 15;
      int gr = row0 + r;
      if (gr < M){
        uint4 q = *(const uint4*)&Ct[r * CS + ch * 8];
        *(uint4*)(outb + (size_t)gr * 64 + ch * 4) = q;
      }
    }
  }
}

// ---------- phase 1: fp8 table, 2 nodes/wave, software-pipelined 16-deep gathers ----------
// ce.x holds src<<5: gather index is (A.x + ln) directly
__global__ __launch_bounds__(256) void k_phase1(const u32* xws8, const int* row_ptr, const int2* ce,
                                                const float* dinv, const float* b_gcn, u32* h8, int n){
  int lane = threadIdx.x & 63;
  int ln = lane & 31;
  int v = blockIdx.x * 8 + ((threadIdx.x >> 6) << 1) + (lane >> 5);
  if (v >= n) return;
  u32 sp = xws8[(size_t)v * 32 + ln];
  float a0 = 0.f, a1 = 0.f, a2 = 0.f, a3 = 0.f;
  acc_fp8(sp, a0, a1, a2, a3);
  int e0 = row_ptr[v], e1 = row_ptr[v + 1];
  int i = e0;
  u32 q0=0,q1=0,q2=0,q3=0,q4=0,q5=0,q6=0,q7=0;
  if (i < e1){
    const int4* cp = (const int4*)(ce + i);
    int4 A = cp[0], B = cp[1], C = cp[2], D = cp[3];
    q0 = xws8[A.x + ln]; q1 = xws8[A.z + ln];
    q2 = xws8[B.x + ln]; q3 = xws8[B.z + ln];
    q4 = xws8[C.x + ln]; q5 = xws8[C.z + ln];
    q6 = xws8[D.x + ln]; q7 = xws8[D.z + ln];
  }
  for (; i + 8 < e1; i += 8){
    const int4* cp2 = (const int4*)(ce + i + 8);
    int4 A = cp2[0], B = cp2[1], C = cp2[2], D = cp2[3];
    u32 p0 = xws8[A.x + ln], p1 = xws8[A.z + ln];
    u32 p2 = xws8[B.x + ln], p3 = xws8[B.z + ln];
    u32 p4 = xws8[C.x + ln], p5 = xws8[C.z + ln];
    u32 p6 = xws8[D.x + ln], p7 = xws8[D.z + ln];
    acc_fp8(q0, a0, a1, a2, a3); acc_fp8(q1, a0, a1, a2, a3);
    acc_fp8(q2, a0, a1, a2, a3); acc_fp8(q3, a0, a1, a2, a3);
    acc_fp8(q4, a0, a1, a2, a3); acc_fp8(q5, a0, a1, a2, a3);
    acc_fp8(q6, a0, a1, a2, a3); acc_fp8(q7, a0, a1, a2, a3);
    q0=p0; q1=p1; q2=p2; q3=p3; q4=p4; q5=p5; q6=p6; q7=p7;
  }
  if (i < e1){
    acc_fp8(q0, a0, a1, a2, a3); acc_fp8(q1, a0, a1, a2, a3);
    acc_fp8(q2, a0, a1, a2, a3); acc_fp8(q3, a0, a1, a2, a3);
    acc_fp8(q4, a0, a1, a2, a3); acc_fp8(q5, a0, a1, a2, a3);
    acc_fp8(q6, a0, a1, a2, a3); acc_fp8(q7, a0, a1, a2, a3);
  }
  float dv = dinv[v];
  float4 bg = *(const float4*)(b_gcn + ln * 4);
  a0 = fmaxf(fmaf(dv, a0, bg.x), 0.f);
  a1 = fmaxf(fmaf(dv, a1, bg.y), 0.f);
  a2 = fmaxf(fmaf(dv, a2, bg.z), 0.f);
  a3 = fmaxf(fmaf(dv, a3, bg.w), 0.f);
  h8[(size_t)v * 32 + ln] = pack_fp8(a0, a1, a2, a3);
}

// ---------- phase 2: fp8 h-table + bf16 ea-table, interleaved ce ----------
__global__ __launch_bounds__(256) void k_phase2(const u32* h8, const int* row_ptr, const int2* ce,
                                                const u16* ea_bf, const float* degf,
                                                u16* A2b, int n){
  int lane = threadIdx.x & 63;
  int ln = lane & 31;
  int half = lane >> 5;
  int v = blockIdx.x * 8 + ((threadIdx.x >> 6) << 1) + half;
  if (v >= n) return;
  u32 sp = h8[(size_t)v * 32 + ln];
  float a0 = 0.f, a1 = 0.f, a2 = 0.f, a3 = 0.f;
  acc_fp8(sp, a0, a1, a2, a3);
  float es = 0.f;                  // channel ln&15, slot-group ln>>4 (4 edges each)
  int ch = ln & 15, grp = ln >> 4;
  int nmark = n << 5;
  int e0 = row_ptr[v], e1 = row_ptr[v + 1];
  int i = e0;
  u32 q0=0,q1=0,q2=0,q3=0,q4=0,q5=0,q6=0,q7=0;
  int4 A = {0,0,0,0}, B = {0,0,0,0}, C = {0,0,0,0}, D = {0,0,0,0};
  if (i < e1){
    const int4* cp = (const int4*)(ce + i);
    A = cp[0]; B = cp[1]; C = cp[2]; D = cp[3];
    q0 = h8[A.x + ln]; q1 = h8[A.z + ln];
    q2 = h8[B.x + ln]; q3 = h8[B.z + ln];
    q4 = h8[C.x + ln]; q5 = h8[C.z + ln];
    q6 = h8[D.x + ln]; q7 = h8[D.z + ln];
  }
  for (; i + 8 < e1; i += 8){
    const int4* cp2 = (const int4*)(ce + i + 8);
    int4 A2 = cp2[0], B2 = cp2[1], C2 = cp2[2], D2 = cp2[3];
    // ea slots for CURRENT block from regs (grp 0 -> A,B; grp 1 -> C,D)
    int s0x = grp ? C.x : A.x, s0e = grp ? C.y : A.y;
    int s1x = grp ? C.z : A.z, s1e = grp ? C.w : A.w;
    int s2x = grp ? D.x : B.x, s2e = grp ? D.y : B.y;
    int s3x = grp ? D.z : B.z, s3e = grp ? D.w : B.w;
    float v0 = bf_lo((u32)ea_bf[(size_t)s0e * 16 + ch]);
    float v1 = bf_lo((u32)ea_bf[(size_t)s1e * 16 + ch]);
    float v2 = bf_lo((u32)ea_bf[(size_t)s2e * 16 + ch]);
    float v3 = bf_lo((u32)ea_bf[(size_t)s3e * 16 + ch]);
    // next block's gathers
    u32 p0 = h8[A2.x + ln], p1 = h8[A2.z + ln];
    u32 p2 = h8[B2.x + ln], p3 = h8[B2.z + ln];
    u32 p4 = h8[C2.x + ln], p5 = h8[C2.z + ln];
    u32 p6 = h8[D2.x + ln], p7 = h8[D2.z + ln];
    // consume current
    acc_fp8(q0, a0, a1, a2, a3); acc_fp8(q1, a0, a1, a2, a3);
    acc_fp8(q2, a0, a1, a2, a3); acc_fp8(q3, a0, a1, a2, a3);
    acc_fp8(q4, a0, a1, a2, a3); acc_fp8(q5, a0, a1, a2, a3);
    acc_fp8(q6, a0, a1, a2, a3); acc_fp8(q7, a0, a1, a2, a3);
    es = fmaf((s0x != nmark) ? 1.f : 0.f, v0, es);
    es = fmaf((s1x != nmark) ? 1.f : 0.f, v1, es);
    es = fmaf((s2x != nmark) ? 1.f : 0.f, v2, es);
    es = fmaf((s3x != nmark) ? 1.f : 0.f, v3, es);
    q0=p0; q1=p1; q2=p2; q3=p3; q4=p4; q5=p5; q6=p6; q7=p7;
    A=A2; B=B2; C=C2; D=D2;
  }
  if (i < e1){
    int s0x = grp ? C.x : A.x, s0e = grp ? C.y : A.y;
    int s1x = grp ? C.z : A.z, s1e = grp ? C.w : A.w;
    int s2x = grp ? D.x : B.x, s2e = grp ? D.y : B.y;
    int s3x = grp ? D.z : B.z, s3e = grp ? D.w : B.w;
    float v0 = bf_lo((u32)ea_bf[(size_t)s0e * 16 + ch]);
    float v1 = bf_lo((u32)ea_bf[(size_t)s1e * 16 + ch]);
    float v2 = bf_lo((u32)ea_bf[(size_t)s2e * 16 + ch]);
    float v3 = bf_lo((u32)ea_bf[(size_t)s3e * 16 + ch]);
    acc_fp8(q0, a0, a1, a2, a3); acc_fp8(q1, a0, a1, a2, a3);
    acc_fp8(q2, a0, a1, a2, a3); acc_fp8(q3, a0, a1, a2, a3);
    acc_fp8(q4, a0, a1, a2, a3); acc_fp8(q5, a0, a1, a2, a3);
    acc_fp8(q6, a0, a1, a2, a3); acc_fp8(q7, a0, a1, a2, a3);
    es = fmaf((s0x != nmark) ? 1.f : 0.f, v0, es);
    es = fmaf((s1x != nmark) ? 1.f : 0.f, v1, es);
    es = fmaf((s2x != nmark) ? 1.f : 0.f, v2, es);
    es = fmaf((s3x != nmark) ? 1.f : 0.f, v3, es);
  }
  // within-half reduction over the 2 slot groups, then wave-uniform pair pick
  es += __shfl_xor(es, 16);
  float c0v = __shfl(es, half * 32 + (ln & 7) * 2);
  float c1v = __shfl(es, half * 32 + (ln & 7) * 2 + 1);
  u32* rowp = (u32*)(A2b + (size_t)v * 160);
  uint2 o; o.x = fpack2(a0, a1); o.y = fpack2(a2, a3);
  *(uint2*)(rowp + ln * 2) = o;
  if (ln < 8){
    rowp[64 + ln] = fpack2(c0v + 1.0f, c1v + 1.0f);
  } else if (ln < 16){
    rowp[64 + ln] = (ln == 8) ? (u32)f2bf(degf[v]) : 0u;
  }
}

// ---------- final: mean + linear (pool partials come from gemm2's fused epilogue) ----------
__global__ __launch_bounds__(128) void k_poolb_final(const float* poolp, const int* start,
                                                     const float* W_out, const float* b_out,
                                                     float* out){
  __shared__ float pl[DH];
  int g = blockIdx.x, c = threadIdx.x;
  int cntg = start[g + 1] - start[g]; if (cntg < 1) cntg = 1;
  pl[c] = poolp[g * DO + c] / (float)cntg;
  __syncthreads();
  float acc = b_out[c];
  for (int k = 0; k < DH; ++k) acc += pl[k] * W_out[k * DO + c];
  out[g * DO + c] = acc;
}

extern "C" void kernel_launch(void* const* d_in, const int* in_sizes, int n_in,
                              void* d_out, int out_size, void* d_ws, size_t ws_size,
                              hipStream_t stream){
  const float* x         = (const float*)d_in[0];
  const int*   edge_index= (const int*)  d_in[1];
  const float* edge_attr = (const float*)d_in[2];
  const int*   batch     = (const int*)  d_in[3];
  const float* W_gcn     = (const float*)d_in[4];
  const float* b_gcn     = (const float*)d_in[5];
  const float* W_le      = (const float*)d_in[6];
  const float* b_le      = (const float*)d_in[7];
  const float* W_lin     = (const float*)d_in[8];
  const float* b_lin     = (const float*)d_in[9];
  const float* W_out     = (const float*)d_in[10];
  const float* b_out     = (const float*)d_in[11];
  float* out = (float*)d_out;

  const int n  = in_sizes[0] / DV;       // 100000
  const int e2 = in_sizes[1] / 2;        // 1600000 directed edges
  const int g  = out_size / DO;          // 64
  const int* srcp = edge_index;
  const int* dstp = edge_index + e2;
  const int e2pad = e2 + 7 * n + 8;      // CSR capacity with per-row pad-to-8

  char* ws = (char*)d_ws;
  size_t off = 0;
  auto alloc = [&](size_t bytes) -> char* {
    char* p = ws + off; off = (off + bytes + 255) & ~(size_t)255; return p;
  };

  int*   cnt     = (int*)  alloc((size_t)n * 4);
  int*   row_ptr = (int*)  alloc((size_t)(n + 1) * 4);
  int*   rank    = (int*)  alloc((size_t)e2 * 4);
  int*   partial = (int*)  alloc((size_t)n * 4);
  int*   bsums   = (int*)  alloc(512);
  int*   bexc    = (int*)  alloc(512);
  float* dinv    = (float*)alloc((size_t)n * 4);
  float* degf    = (float*)alloc((size_t)n * 4);
  int*   startg  = (int*)  alloc((size_t)(g + 1) * 4);
  float* poolp   = (float*)alloc((size_t)g * DO * 4);
  float* Wfull   = (float*)alloc(160 * DH * 4);
  u32*   h8      = (u32*)  alloc((size_t)(n + 1) * 128);   // fp8 rows, +1 zero row
  int2*  ce      = (int2*) alloc((size_t)e2pad * 8);
  u32*   ea_bf   = (u32*)  alloc((size_t)e2 * 16);         // bf16 ea table: E rows x 16ch x 2B
  // region A: xws8 (fp8, [N+1,128B]) later overwritten by A2 (bf16, [N,160])
  size_t szXW = (size_t)(n + 1) * 128, szA2 = (size_t)n * 160 * 2;
  char* regionA = alloc(szA2 > szXW ? szA2 : szXW);
  u32* xws8 = (u32*)regionA;
  u16* A2b  = (u16*)regionA;

  const int nb1024 = (n + 1023) / 1024;  // must be <= 128 for k_scan2

  k_init      <<<(n + 255) / 256, 256, 0, stream>>>(cnt, poolp, n, g * DO);
  k_count     <<<(e2 + 255) / 256, 256, 0, stream>>>(dstp, edge_attr, cnt, rank, ea_bf, e2);
  k_scan1     <<<nb1024, 256, 0, stream>>>(cnt, partial, bsums, n);
  k_scan2     <<<1, 128, 0, stream>>>(bsums, bexc, nb1024);
  k_scan3f    <<<(n + 255) / 256, 256, 0, stream>>>(partial, bexc, row_ptr, cnt, dinv, degf,
                                                    batch, startg, n, g);
  k_scatterpad<<<(e2 + 255) / 256, 256, 0, stream>>>(srcp, dstp, rank, row_ptr, cnt, ce,
                                                     xws8 + (size_t)n * 32, h8 + (size_t)n * 32,
                                                     e2, n);
  k_wcombo    <<<160, 128, 0, stream>>>(W_lin, b_lin, W_le, b_le, Wfull);

  k_gemm_mfma<DV, false, false, true, true, false>
      <<<(n + 63) / 64, 256, 0, stream>>>(x, W_gcn, xws8, dinv, n, nullptr, nullptr);
  k_phase1    <<<(n + 7) / 8, 256, 0, stream>>>(xws8, row_ptr, ce, dinv, b_gcn, h8, n);
  k_phase2    <<<(n + 7) / 8, 256, 0, stream>>>(h8, row_ptr, ce,
                                                (const u16*)ea_bf, degf, A2b, n);
  k_gemm_mfma<160, true, true, false, false, true>
      <<<(n + 63) / 64, 256, 0, stream>>>(A2b, Wfull, (u32*)nullptr, (const float*)nullptr,
                                          n, batch, poolp);
  k_poolb_final<<<g, 128, 0, stream>>>(poolp, startg, W_out, b_out, out);
}